// Round 13
// baseline (452.196 us; speedup 1.0000x reference)
//
#include <hip/hip_runtime.h>
#include <cmath>

#define T 512
#define HID 64
#define BLK_B 32       // batch per block: two halves of 16
#define TS 32          // timesteps per staged x-chunk
#define LOG2E 1.44269504f

typedef __attribute__((ext_vector_type(8))) _Float16 f16x8;
typedef __attribute__((ext_vector_type(4))) float f32x4;

__device__ __forceinline__ float fast_rcp(float x) { return __builtin_amdgcn_rcpf(x); }
__device__ __forceinline__ float fast_exp2(float x) { return __builtin_amdgcn_exp2f(x); }
__device__ __forceinline__ float sig_f(float x) {
    return fast_rcp(1.0f + fast_exp2(-LOG2E * x));
}
__device__ __forceinline__ float th_f(float x) {
    return 1.0f - 2.0f * fast_rcp(1.0f + fast_exp2((2.0f * LOG2E) * x));
}

#define MFMA(a, b, c) __builtin_amdgcn_mfma_f32_16x16x32_f16((a), (b), (c), 0, 0, 0)

// Role-split LSTM: waves 0-3 = M (MFMA gate producer), waves 4-7 = A
// (activation/state consumer). Two batch halves ping-pong so M and A are
// always both busy (matrix pipe ∥ trans pipe). Verified 16x16x32 lane
// mapping (r7-r12): A-op lane&15 = gate row, k = grp*8+e; B-op lane&15 =
// batch col; D col = lane&15, row = grp*4+reg.
__global__ __launch_bounds__(512) void lstm_rs_kernel(
    const float* __restrict__ x,      // [B, T, 8]
    const float* __restrict__ W_ih,   // [256, 8]
    const float* __restrict__ W_hh,   // [256, 64]
    const float* __restrict__ b_ih,   // [256]
    const float* __restrict__ b_hh,   // [256]
    const float* __restrict__ W_fc,   // [2, 64]
    const float* __restrict__ b_fc,   // [2]
    float* __restrict__ out)          // [B, 2]
{
    // 63KB arena -> allocator occupancy target 2 blocks/CU (16 waves) ->
    // 128-VGPR budget for ~115 live set (occupancy-target model, r3-r12).
    __shared__ alignas(16) float arena[16128];               // 63 KB
    float*     gbase = arena;                        // [2][16cb][4q][16] f32 gates (8192 f)
    _Float16*  xb    = (_Float16*)(arena + 8192);    // [TS][32][8] f16      (8192 h)
    _Float16*  hbase = xb + 8192;                    // [2][16][72] f16      (2304 h)

    const int tid  = threadIdx.x;
    const int wv   = tid >> 6;        // 0..7
    const int lane = tid & 63;
    const int colb = lane & 15;       // batch col within half
    const int grp  = lane >> 4;       // k-slice / row-quad group
    const int batch0 = blockIdx.x * BLK_B;
    const bool isM = (wv < 4);
    const int w = isM ? wv : (wv - 4);   // j-block index [16w,16w+16)

    // ---- persistent A-frags: W_hh f16 (2 k-tiles), W_ih packed tile ----
#define DECL_Q(q) f16x8 whi##q##_0, whi##q##_1, wih##q; f32x4 bias##q;
    DECL_Q(0) DECL_Q(1) DECL_Q(2) DECL_Q(3)
#undef DECL_Q
    f16x8 zz;
    #pragma unroll
    for (int e = 0; e < 8; ++e) zz[e] = (_Float16)0.0f;

#define LOAD_Q(q) {                                                        \
        int gate = 64 * q + 16 * w + colb;                                 \
        const float* wr = W_hh + gate * 64 + grp * 8;                      \
        _Pragma("unroll")                                                  \
        for (int e = 0; e < 8; ++e) {                                      \
            whi##q##_0[e] = (_Float16)wr[e];                               \
            whi##q##_1[e] = (_Float16)wr[32 + e];                          \
        }                                                                  \
        const float* wi = W_ih + gate * 8;                                 \
        f16x8 ih;                                                          \
        _Pragma("unroll")                                                  \
        for (int e = 0; e < 8; ++e) ih[e] = (_Float16)wi[e];               \
        wih##q = (grp == 0) ? ih : zz;                                     \
        int gb = 64 * q + 16 * w + grp * 4;                                \
        bias##q.x = b_ih[gb + 0] + b_hh[gb + 0];                           \
        bias##q.y = b_ih[gb + 1] + b_hh[gb + 1];                           \
        bias##q.z = b_ih[gb + 2] + b_hh[gb + 2];                           \
        bias##q.w = b_ih[gb + 3] + b_hh[gb + 3];                           \
    }
    LOAD_Q(0) LOAD_Q(1) LOAD_Q(2) LOAD_Q(3)
#undef LOAD_Q

    // zero both h halves
    for (int i = tid; i < 2304; i += 512) hbase[i] = (_Float16)0.0f;

    f32x4 c0v = {0, 0, 0, 0};   // A-wave: c states for half 0
    f32x4 c1v = {0, 0, 0, 0};   // A-wave: c states for half 1

    // ---- M phase: gates(half, t) -> gbase[half], f32, XOR-swizzled b128 ----
#define STG(gh, q, acc) {                                                  \
        int i16 = (((colb * 4 + (q)) * 16) + 4 * w + grp) ^ colb;          \
        *(f32x4*)((gh) + i16 * 4) = acc;                                   \
    }
#define MPH(half, tmod) {                                                  \
        const _Float16* hb = hbase + (half) * 1152 + colb * 72 + grp * 8;  \
        f16x8 bh0 = *(const f16x8*)(hb);                                   \
        f16x8 bh1 = *(const f16x8*)(hb + 32);                              \
        f16x8 bx  = *(const f16x8*)(xb + (tmod) * 256 + (half) * 128 + colb * 8); \
        f32x4 a0 = MFMA(wih0, bx, bias0);                                  \
        a0 = MFMA(whi0_0, bh0, a0);  a0 = MFMA(whi0_1, bh1, a0);           \
        f32x4 a1 = MFMA(wih1, bx, bias1);                                  \
        a1 = MFMA(whi1_0, bh0, a1);  a1 = MFMA(whi1_1, bh1, a1);           \
        f32x4 a2 = MFMA(wih2, bx, bias2);                                  \
        a2 = MFMA(whi2_0, bh0, a2);  a2 = MFMA(whi2_1, bh1, a2);           \
        f32x4 a3 = MFMA(wih3, bx, bias3);                                  \
        a3 = MFMA(whi3_0, bh0, a3);  a3 = MFMA(whi3_1, bh1, a3);           \
        float* gh = gbase + (half) * 4096;                                 \
        STG(gh, 0, a0) STG(gh, 1, a1) STG(gh, 2, a2) STG(gh, 3, a3)        \
    }

    // ---- A phase: gates(half) -> activations -> c,h update ----
#define APH(half, CV) {                                                    \
        const float* gh = gbase + (half) * 4096;                           \
        int i0 = (((colb * 4 + 0) * 16) + 4 * w + grp) ^ colb;             \
        int i1 = (((colb * 4 + 1) * 16) + 4 * w + grp) ^ colb;             \
        int i2 = (((colb * 4 + 2) * 16) + 4 * w + grp) ^ colb;             \
        int i3 = (((colb * 4 + 3) * 16) + 4 * w + grp) ^ colb;             \
        f32x4 ai = *(const f32x4*)(gh + i0 * 4);                           \
        f32x4 af = *(const f32x4*)(gh + i1 * 4);                           \
        f32x4 ag = *(const f32x4*)(gh + i2 * 4);                           \
        f32x4 ao = *(const f32x4*)(gh + i3 * 4);                           \
        float gi0 = sig_f(ai.x), gi1 = sig_f(ai.y), gi2 = sig_f(ai.z), gi3 = sig_f(ai.w); \
        float gf0 = sig_f(af.x), gf1 = sig_f(af.y), gf2 = sig_f(af.z), gf3 = sig_f(af.w); \
        float gg0 = th_f(ag.x),  gg1 = th_f(ag.y),  gg2 = th_f(ag.z),  gg3 = th_f(ag.w);  \
        float go0 = sig_f(ao.x), go1 = sig_f(ao.y), go2 = sig_f(ao.z), go3 = sig_f(ao.w); \
        CV.x = fmaf(gf0, CV.x, gi0 * gg0);                                 \
        CV.y = fmaf(gf1, CV.y, gi1 * gg1);                                 \
        CV.z = fmaf(gf2, CV.z, gi2 * gg2);                                 \
        CV.w = fmaf(gf3, CV.w, gi3 * gg3);                                 \
        float h0 = go0 * th_f(CV.x);                                       \
        float h1 = go1 * th_f(CV.y);                                       \
        float h2 = go2 * th_f(CV.z);                                       \
        float h3 = go3 * th_f(CV.w);                                       \
        auto p01 = __builtin_amdgcn_cvt_pkrtz(h0, h1);                     \
        auto p23 = __builtin_amdgcn_cvt_pkrtz(h2, h3);                     \
        uint2 st;                                                          \
        st.x = __builtin_bit_cast(unsigned int, p01);                      \
        st.y = __builtin_bit_cast(unsigned int, p23);                      \
        *(uint2*)(hbase + (half) * 1152 + colb * 72 + 16 * w + grp * 4) = st; \
    }

    // ---- x staging: 32 timesteps x 32 batch, f16, all 512 threads ----
#define STAGE(tstart) {                                                    \
        int sb = tid >> 4, st_ = tid & 15;                                 \
        _Pragma("unroll")                                                  \
        for (int r = 0; r < 2; ++r) {                                      \
            int tt = st_ + r * 16;                                         \
            const float* xg = x + ((size_t)(batch0 + sb) * T + (tstart) + tt) * 8; \
            f16x8 v;                                                       \
            _Pragma("unroll")                                              \
            for (int e = 0; e < 8; ++e) v[e] = (_Float16)xg[e];            \
            *(f16x8*)(xb + (tt * 32 + sb) * 8) = v;                        \
        }                                                                  \
    }

    STAGE(0)
    __syncthreads();          // x chunk 0 + h zero-init visible

    // phase 0: M computes gates_H0(t=0); A idle
    if (isM) { MPH(0, 0) }
    __syncthreads();

    #pragma unroll 1
    for (int t = 0; t < T; ++t) {
        const int tmod = t & (TS - 1);
        // odd phase: M gates_H1(t) | A update H0(t)
        if (isM) { MPH(1, tmod) } else { APH(0, c0v) }
        __syncthreads();
        if (t == T - 1) break;
        if (((t + 1) & (TS - 1)) == 0) {
            STAGE(t + 1)
            __syncthreads();
        }
        // even phase: M gates_H0(t+1) | A update H1(t)
        if (isM) { MPH(0, (t + 1) & (TS - 1)) } else { APH(1, c1v) }
        __syncthreads();
    }
    // epilogue: A update H1(T-1)
    if (!isM) { APH(1, c1v) }
    __syncthreads();

    // ---- final FC: thread -> (b = tid>>4 of 32, j-quad = tid&15) ----
    {
        int b = tid >> 4, q4 = (tid & 15) * 4;
        const _Float16* ph = hbase + (b >> 4) * 1152 + (b & 15) * 72 + q4;
        float h0 = (float)ph[0];
        float h1 = (float)ph[1];
        float h2 = (float)ph[2];
        float h3 = (float)ph[3];
        float s0 = h0 * W_fc[q4] + h1 * W_fc[q4 + 1] + h2 * W_fc[q4 + 2] + h3 * W_fc[q4 + 3];
        float s1 = h0 * W_fc[64 + q4] + h1 * W_fc[64 + q4 + 1] + h2 * W_fc[64 + q4 + 2] + h3 * W_fc[64 + q4 + 3];
        #pragma unroll
        for (int off = 1; off < 16; off <<= 1) {
            s0 += __shfl_xor(s0, off, 64);
            s1 += __shfl_xor(s1, off, 64);
        }
        if ((tid & 15) == 0) {
            out[(size_t)(batch0 + b) * 2 + 0] = s0 + b_fc[0];
            out[(size_t)(batch0 + b) * 2 + 1] = s1 + b_fc[1];
        }
    }
#undef MPH
#undef APH
#undef STG
#undef STAGE
}

extern "C" void kernel_launch(void* const* d_in, const int* in_sizes, int n_in,
                              void* d_out, int out_size, void* d_ws, size_t ws_size,
                              hipStream_t stream) {
    const float* x    = (const float*)d_in[0];
    const float* W_ih = (const float*)d_in[1];
    const float* W_hh = (const float*)d_in[2];
    const float* b_ih = (const float*)d_in[3];
    const float* b_hh = (const float*)d_in[4];
    const float* W_fc = (const float*)d_in[5];
    const float* b_fc = (const float*)d_in[6];
    float* out = (float*)d_out;

    dim3 grid(8192 / BLK_B);   // 256 blocks = 1 per CU
    dim3 block(512);
    lstm_rs_kernel<<<grid, block, 0, stream>>>(x, W_ih, W_hh, b_ih, b_hh,
                                               W_fc, b_fc, out);
}